// Round 6
// baseline (969.939 us; speedup 1.0000x reference)
//
#include <hip/hip_runtime.h>
#include <stdint.h>

#define NNODES 50000
#define NEDGES 800000
#define NGRAPH 100
#define NCHUNK32 (NEDGES / 32)   // 25000 32-edge chunks
#define NB0 196                  // mlp blocks for 50000 rows (256/block)

typedef _Float16 f16;
typedef __attribute__((ext_vector_type(8))) _Float16 half8;
typedef __attribute__((ext_vector_type(4))) _Float16 half4;
typedef __attribute__((ext_vector_type(4))) float floatx4;

// stage 128x128 fp32 row-major W[k][n] -> LDS WT[n][136 pad] fp16, float4 loads
__device__ __forceinline__ void stage_WT(const float* __restrict__ W, f16* WT,
                                         int tid, int nthr) {
    for (int idx = tid; idx < 128 * 32; idx += nthr) {
        int k = idx >> 5, n4 = (idx & 31) * 4;
        floatx4 v = *(const floatx4*)(W + k * 128 + n4);
        WT[(n4 + 0) * 136 + k] = (f16)v[0];
        WT[(n4 + 1) * 136 + k] = (f16)v[1];
        WT[(n4 + 2) * 136 + k] = (f16)v[2];
        WT[(n4 + 3) * 136 + k] = (f16)v[3];
    }
}

__device__ __forceinline__ float fast_tanh(float x) {
    x = fminf(fmaxf(x, -15.0f), 15.0f);
    float e2 = __expf(2.0f * x);
    return (e2 - 1.0f) * __builtin_amdgcn_rcpf(e2 + 1.0f);
}

// transposed-m for 32-edge chunks: column c owns f16 elements [c*32, c*32+32);
// 8 groups of 4 edges, rotated by (c>>1) so E-writes/F-reads spread bank-pairs
// evenly (16 distinct bank-pairs per instruction). Bijective per column.
__device__ __forceinline__ int mt32(int c, int g) {
    return c * 32 + ((((c >> 1) + g) & 7) << 2);
}

__global__ void init_k(float* out, int osz, int* cnt) {
    int i = blockIdx.x * 256 + threadIdx.x;
    if (i < osz) out[i] = 0.0f;
    if (i < NNODES) cnt[i] = 0;
}

__global__ void hist_k(const int* __restrict__ dst, int* __restrict__ cnt) {
    int e = blockIdx.x * 256 + threadIdx.x;
    if (e < NEDGES) atomicAdd(&cnt[dst[e]], 1);
}

__global__ __launch_bounds__(1024) void scan1_k(const int* __restrict__ cnt,
                                                int* __restrict__ rowStart,
                                                int* __restrict__ blockSum) {
    __shared__ int buf[1024];
    int tid = threadIdx.x;
    int i = blockIdx.x * 1024 + tid;
    int v = (i < NNODES) ? cnt[i] : 0;
    buf[tid] = v;
    __syncthreads();
    for (int off = 1; off < 1024; off <<= 1) {
        int t = (tid >= off) ? buf[tid - off] : 0;
        __syncthreads();
        buf[tid] += t;
        __syncthreads();
    }
    if (i < NNODES) rowStart[i] = buf[tid] - v;
    if (tid == 1023) blockSum[blockIdx.x] = buf[1023];
}

__global__ void scan2_k(int* __restrict__ blockSum, int nb) {
    if (threadIdx.x == 0) {
        int run = 0;
        for (int b = 0; b < nb; ++b) { int s = blockSum[b]; blockSum[b] = run; run += s; }
    }
}

__global__ __launch_bounds__(1024) void scan3_k(int* __restrict__ rowStart,
                                                const int* __restrict__ blockSum,
                                                int* __restrict__ cnt) {
    int i = blockIdx.x * 1024 + threadIdx.x;
    if (i < NNODES) { rowStart[i] += blockSum[blockIdx.x]; cnt[i] = 0; }
    if (i == 0) rowStart[NNODES] = NEDGES;
}

__global__ void scatter_k(const int* __restrict__ src, const int* __restrict__ et,
                          const int* __restrict__ dst, const float* __restrict__ dist,
                          const int* __restrict__ rowStart, int* __restrict__ cnt,
                          uint4* __restrict__ packE) {
    int e = blockIdx.x * 256 + threadIdx.x;
    if (e >= NEDGES) return;
    int d = dst[e];
    int pos = rowStart[d] + atomicAdd(&cnt[d], 1);
    uint4 pk;
    pk.x = (unsigned)src[e];
    pk.y = (unsigned)et[e];
    pk.z = (unsigned)d;
    pk.w = __float_as_uint(dist[e]);
    packE[pos] = pk;
}

__global__ void gather_h(const int* __restrict__ nt, const float* __restrict__ emb,
                         float* __restrict__ h) {
    int i = blockIdx.x * 256 + threadIdx.x;
    int row = i >> 5, c4 = (i & 31) * 4;
    if (row < NNODES)
        *(floatx4*)(h + row * 128 + c4) = *(const floatx4*)(emb + nt[row] * 128 + c4);
}

// ---------------------------------------------------------------------------
// Fused node-MLP + edge-type-table kernel (one launch per layer):
//   blocks [0, NB0)      : P = relu(h@Wn1+bn1)@Wn2+bn2      (50000 rows)
//   blocks [NB0, NB0+2)  : T = edge_emb@We1[:128]+be1        (500 rows)
// ---------------------------------------------------------------------------
__global__ __launch_bounds__(1024, 4) void mlp_combo(
        const float* __restrict__ Xh,
        const float* __restrict__ W1, const float* __restrict__ b1,
        const float* __restrict__ W2, const float* __restrict__ b2,
        f16* __restrict__ OutP,
        const float* __restrict__ Xe,
        const float* __restrict__ We1, const float* __restrict__ be1,
        f16* __restrict__ OutT) {
    __shared__ f16 W1T[128 * 136];
    __shared__ f16 W2T[128 * 136];
    __shared__ f16 xBuf[256 * 136];
    __shared__ float bias1[128];
    __shared__ float bias2[128];
    int tid = threadIdx.x;
    bool mode2 = blockIdx.x >= NB0;

    const float* X  = mode2 ? Xe : Xh;
    const float* Wa = mode2 ? We1 : W1;
    const float* ba = mode2 ? be1 : b1;
    f16* Out        = mode2 ? OutT : OutP;
    int  M          = mode2 ? 500 : NNODES;
    int  r0         = (mode2 ? (blockIdx.x - NB0) : blockIdx.x) * 256;

    stage_WT(Wa, W1T, tid, 1024);
    if (!mode2) stage_WT(W2, W2T, tid, 1024);
    if (tid < 128) { bias1[tid] = ba[tid]; bias2[tid] = mode2 ? 0.0f : b2[tid]; }

    for (int it = 0; it < 8; ++it) {
        int row = it * 32 + (tid >> 5);
        int c4 = (tid & 31) * 4;
        int gr = r0 + row;
        floatx4 x = {0.0f, 0.0f, 0.0f, 0.0f};
        if (gr < M) x = *(const floatx4*)(X + (size_t)gr * 128 + c4);
        half4 xh;
        xh[0] = (f16)x[0]; xh[1] = (f16)x[1]; xh[2] = (f16)x[2]; xh[3] = (f16)x[3];
        *(half4*)(xBuf + row * 136 + c4) = xh;
    }
    __syncthreads();

    int lane = tid & 63, wv = tid >> 6;
    int R = wv * 16;
    int n16 = lane & 15, q = lane >> 4;
    int gr = r0 + R + n16;

    half8 a[4];
    #pragma unroll
    for (int kk = 0; kk < 4; ++kk)
        a[kk] = *(const half8*)(xBuf + (R + n16) * 136 + kk * 32 + q * 8);

    #pragma unroll
    for (int f = 0; f < 8; ++f) {
        floatx4 acc = *(const floatx4*)(bias1 + f * 16 + q * 4);
        #pragma unroll
        for (int kk = 0; kk < 4; ++kk) {
            half8 aw = *(const half8*)(W1T + (f * 16 + n16) * 136 + kk * 32 + q * 8);
            acc = __builtin_amdgcn_mfma_f32_16x16x32_f16(aw, a[kk], acc, 0, 0, 0);
        }
        if (!mode2) {
            half4 y;
            #pragma unroll
            for (int i = 0; i < 4; ++i) y[i] = (f16)fmaxf(acc[i], 0.0f);
            *(half4*)(xBuf + (R + n16) * 136 + f * 16 + q * 4) = y;
        } else {
            half4 o;
            #pragma unroll
            for (int i = 0; i < 4; ++i) o[i] = (f16)acc[i];
            if (gr < M) *(half4*)(Out + (size_t)gr * 128 + f * 16 + q * 4) = o;
        }
    }

    if (!mode2) {
        #pragma unroll
        for (int kk = 0; kk < 4; ++kk)
            a[kk] = *(const half8*)(xBuf + (R + n16) * 136 + kk * 32 + q * 8);
        #pragma unroll
        for (int f = 0; f < 8; ++f) {
            floatx4 acc = *(const floatx4*)(bias2 + f * 16 + q * 4);
            #pragma unroll
            for (int kk = 0; kk < 4; ++kk) {
                half8 aw = *(const half8*)(W2T + (f * 16 + n16) * 136 + kk * 32 + q * 8);
                acc = __builtin_amdgcn_mfma_f32_16x16x32_f16(aw, a[kk], acc, 0, 0, 0);
            }
            half4 o;
            #pragma unroll
            for (int i = 0; i < 4; ++i) o[i] = (f16)acc[i];
            if (gr < M) *(half4*)(Out + (size_t)gr * 128 + f * 16 + q * 4) = o;
        }
    }
}

// ---------------------------------------------------------------------------
// Barrier-free edge kernel, 32-edge chunks, 10 WAVES/BLOCK (640 thr).
// R5 (8 waves) showed the 41% b128 cut bought only -6%: the wall is the
// serialized per-chunk phase chain with insufficient wave coverage
// (Occupancy 38->19%). This round buys waves back: the loop-invariant
// B-stage weight W1r (30x128) moves from LDS (10.2 KB + 8 b128/chunk) into
// 32 VGPRs/lane (8x half8, per-(n16,q) static, loaded once at prologue).
// Freed LDS lets 10 waves fit: Uall 10x8704 + 2 weight tables = 158976 B.
// __launch_bounds__(640,3): 170-VGPR budget, est ~156 -> no spill (the R3'
// thrash came from +40 VGPR against a 64-VGPR ceiling; headroom here).
// sched_barrier(0) fences and sbe2/sbc-in-LDS preserved (R8/R10, R3').
// Tripwire: FETCH must stay ~80.6 MB / WRITE ~26 MB; any rise = spill.
// ---------------------------------------------------------------------------
__global__ __launch_bounds__(640, 3) void edge_kernel(
        const uint4* __restrict__ packE,
        const f16* __restrict__ P, const f16* __restrict__ T,
        const float* __restrict__ We1,
        const float* __restrict__ We2, const float* __restrict__ be2,
        const float* __restrict__ Wc,  const float* __restrict__ bc,
        float* __restrict__ h) {
    __shared__ f16 W2T[128 * 136];       // 34816 B
    __shared__ f16 WcT[128 * 136];       // 34816 B
    __shared__ f16 Uall[10 * 4352];      // 87040 B : per-wave 32x136 (T/u/ep) then mT
    __shared__ float sbe2[128], sbc[128];
    __shared__ int dstW[10][32];
    // total 158976 B -> 1 block/CU, 10 waves

    int tid = threadIdx.x;
    stage_WT(We2, W2T, tid, 640);
    stage_WT(Wc,  WcT, tid, 640);
    if (tid < 128) { sbe2[tid] = be2[tid]; sbc[tid] = bc[tid]; }

    int lane = tid & 63, wv = tid >> 6;      // wv 0..9
    int n16 = lane & 15, q = lane >> 4;

    // B-stage weights in registers: w1r[f][j] = We1[128 + q*8+j][f*16+n16]
    // (zero-padded past row 30). Loop-invariant, 32 VGPR, one-time L2 loads.
    half8 w1r[8];
    #pragma unroll
    for (int f = 0; f < 8; ++f) {
        #pragma unroll
        for (int j = 0; j < 8; ++j) {
            int kr = q * 8 + j;
            w1r[f][j] = (kr < 30)
                ? (f16)We1[(size_t)(128 + kr) * 128 + f * 16 + n16]
                : (f16)0.0f;
        }
    }
    __syncthreads();    // weights ready; the ONLY block barrier

    f16* U = Uall + wv * 4352;
    int* dW = dstW[wv];
    const float invgap = 29.0f / 10.0f;
    int colA = lane, colB = lane + 64;
    int tsub = lane & 3, trow = lane >> 2;

    float sbcv[8];
    #pragma unroll
    for (int f = 0; f < 8; ++f) sbcv[f] = sbc[f * 16 + n16];

    // balanced stripe: 25000 chunks over 2560 waves (9 or 10 each)
    int wgid = blockIdx.x * 10 + wv;
    int extra = wgid < 1960 ? wgid : 1960;
    int c0 = wgid * 9 + extra;
    int c1 = c0 + 9 + (wgid < 1960 ? 1 : 0);

    float carry0 = 0.0f, carry1 = 0.0f;
    int prev = -1;

    // prologue: pk for chunk c0 (32 records)
    uint4 pk = {0u, 0u, 0u, 0u};
    if (lane < 32) pk = packE[(size_t)c0 * 32 + lane];

    for (int ch = c0; ch < c1; ++ch) {
        bool hasNext = (ch + 1 < c1);
        // ---- distribute current records -----------------------------------
        int   ety0  = __shfl((int)pk.y, trow);
        int   ety1  = __shfl((int)pk.y, trow + 16);
        int   srcv0 = __shfl((int)pk.x, n16);
        int   srcv1 = __shfl((int)pk.x, n16 + 16);
        float d0    = __shfl(__uint_as_float(pk.w), n16);
        float d1    = __shfl(__uint_as_float(pk.w), n16 + 16);
        if (lane < 32) dW[lane] = (int)pk.z;

        // ---- T loads (both halves), drained into LDS (phase A) ------------
        {
            const uint4* Tp0 = (const uint4*)(T + (size_t)ety0 * 128 + tsub * 32);
            const uint4* Tp1 = (const uint4*)(T + (size_t)ety1 * 128 + tsub * 32);
            uint4 ta0 = Tp0[0], ta1 = Tp0[1], ta2 = Tp0[2], ta3 = Tp0[3];
            uint4 tb0 = Tp1[0], tb1 = Tp1[1], tb2 = Tp1[2], tb3 = Tp1[3];
            uint4* u0 = (uint4*)(U + trow * 136 + tsub * 32);
            uint4* u1 = (uint4*)(U + (16 + trow) * 136 + tsub * 32);
            u0[0] = ta0; u0[1] = ta1; u0[2] = ta2; u0[3] = ta3;
            u1[0] = tb0; u1[1] = tb1; u1[2] = tb2; u1[3] = tb3;
        }
        __builtin_amdgcn_sched_barrier(0);   // T drained before P issues

        // ---- NOW issue P loads (T no longer in flight) --------------------
        half8 pA0, pA1, pA2, pA3, pB0, pB1, pB2, pB3;
        {
            const f16* Pr0 = P + (size_t)srcv0 * 128 + q * 8;
            const f16* Pr1 = P + (size_t)srcv1 * 128 + q * 8;
            pA0 = *(const half8*)(Pr0);      pA1 = *(const half8*)(Pr0 + 32);
            pA2 = *(const half8*)(Pr0 + 64); pA3 = *(const half8*)(Pr0 + 96);
            pB0 = *(const half8*)(Pr1);      pB1 = *(const half8*)(Pr1 + 32);
            pB2 = *(const half8*)(Pr1 + 64); pB3 = *(const half8*)(Pr1 + 96);
        }
        uint4 pkn = {0u, 0u, 0u, 0u};
        if (hasNext && lane < 32) pkn = packE[(size_t)(ch + 1) * 32 + lane];

        // ---- rbf in regs (VALU overlaps P latency) ------------------------
        half8 ar0, ar1;
        #pragma unroll
        for (int j = 0; j < 8; ++j) {
            int k = q * 8 + j;
            float c = (float)k * (10.0f / 29.0f);
            float df0 = d0 - c, df1 = d1 - c;
            ar0[j] = (f16)((k < 30) ? __expf(-df0 * df0 * invgap) : 0.0f);
            ar1[j] = (f16)((k < 30) ? __expf(-df1 * df1 * invgap) : 0.0f);
        }

        // ---- B: u^T = relu(W1r^T @ rbf^T + T^T); reg weights, 2 MFMAs -----
        #pragma unroll
        for (int f = 0; f < 8; ++f) {
            half8 aw = w1r[f];
            f16* up0 = U + n16 * 136 + f * 16 + q * 4;
            f16* up1 = U + (16 + n16) * 136 + f * 16 + q * 4;
            half4 tv0 = *(const half4*)up0;
            half4 tv1 = *(const half4*)up1;
            floatx4 c40 = {(float)tv0[0], (float)tv0[1], (float)tv0[2], (float)tv0[3]};
            floatx4 c41 = {(float)tv1[0], (float)tv1[1], (float)tv1[2], (float)tv1[3]};
            c40 = __builtin_amdgcn_mfma_f32_16x16x32_f16(aw, ar0, c40, 0, 0, 0);
            c41 = __builtin_amdgcn_mfma_f32_16x16x32_f16(aw, ar1, c41, 0, 0, 0);
            half4 uv0, uv1;
            #pragma unroll
            for (int i = 0; i < 4; ++i) {
                uv0[i] = (f16)fmaxf(c40[i], 0.0f);
                uv1[i] = (f16)fmaxf(c41[i], 0.0f);
            }
            *(half4*)up0 = uv0;
            *(half4*)up1 = uv1;
        }

        // ---- C: ep^T = W2^T @ u^T + be2; 1 weight read, 2 MFMAs -----------
        half8 a20[4], a21[4];
        #pragma unroll
        for (int kk = 0; kk < 4; ++kk) {
            a20[kk] = *(const half8*)(U + n16 * 136 + kk * 32 + q * 8);
            a21[kk] = *(const half8*)(U + (16 + n16) * 136 + kk * 32 + q * 8);
        }
        #pragma unroll
        for (int f = 0; f < 8; ++f) {
            floatx4 acc0 = *(const floatx4*)(sbe2 + f * 16 + q * 4);
            floatx4 acc1 = acc0;
            #pragma unroll
            for (int kk = 0; kk < 4; ++kk) {
                half8 aw = *(const half8*)(W2T + (f * 16 + n16) * 136 + kk * 32 + q * 8);
                acc0 = __builtin_amdgcn_mfma_f32_16x16x32_f16(aw, a20[kk], acc0, 0, 0, 0);
                acc1 = __builtin_amdgcn_mfma_f32_16x16x32_f16(aw, a21[kk], acc1, 0, 0, 0);
            }
            half4 ev0, ev1;
            #pragma unroll
            for (int i = 0; i < 4; ++i) { ev0[i] = (f16)acc0[i]; ev1[i] = (f16)acc1[i]; }
            *(half4*)(U + n16 * 136 + f * 16 + q * 4) = ev0;
            *(half4*)(U + (16 + n16) * 136 + f * 16 + q * 4) = ev1;
        }

        // ---- E: m = tanh((P ⊙ ep) @ Wc + bc); 1 weight read, 2 MFMAs ------
        {
            half8 e00 = *(const half8*)(U + n16 * 136 + 0 * 32 + q * 8);
            half8 e01 = *(const half8*)(U + n16 * 136 + 1 * 32 + q * 8);
            half8 e02 = *(const half8*)(U + n16 * 136 + 2 * 32 + q * 8);
            half8 e03 = *(const half8*)(U + n16 * 136 + 3 * 32 + q * 8);
            half8 e10 = *(const half8*)(U + (16 + n16) * 136 + 0 * 32 + q * 8);
            half8 e11 = *(const half8*)(U + (16 + n16) * 136 + 1 * 32 + q * 8);
            half8 e12 = *(const half8*)(U + (16 + n16) * 136 + 2 * 32 + q * 8);
            half8 e13 = *(const half8*)(U + (16 + n16) * 136 + 3 * 32 + q * 8);
            a20[0] = e00 * pA0; a20[1] = e01 * pA1; a20[2] = e02 * pA2; a20[3] = e03 * pA3;
            a21[0] = e10 * pB0; a21[1] = e11 * pB1; a21[2] = e12 * pB2; a21[3] = e13 * pB3;
        }
        #pragma unroll
        for (int f = 0; f < 8; ++f) {
            float bb = sbcv[f];
            floatx4 acc0 = {bb, bb, bb, bb};
            floatx4 acc1 = {bb, bb, bb, bb};
            #pragma unroll
            for (int kk = 0; kk < 4; ++kk) {
                half8 b = *(const half8*)(WcT + (f * 16 + n16) * 136 + kk * 32 + q * 8);
                acc0 = __builtin_amdgcn_mfma_f32_16x16x32_f16(a20[kk], b, acc0, 0, 0, 0);
                acc1 = __builtin_amdgcn_mfma_f32_16x16x32_f16(a21[kk], b, acc1, 0, 0, 0);
            }
            int c = f * 16 + n16;
            half4 mv0, mv1;
            #pragma unroll
            for (int i = 0; i < 4; ++i) {
                mv0[i] = (f16)fast_tanh(acc0[i]);
                mv1[i] = (f16)fast_tanh(acc1[i]);
            }
            *(half4*)(U + mt32(c, q))     = mv0;   // edges q*4..q*4+3
            *(half4*)(U + mt32(c, 4 + q)) = mv1;   // edges 16+q*4..16+q*4+3
        }

        // ---- F: per-col segment reduce over 32 rows with carry ------------
        {
            half4 va[8], vb[8];
            #pragma unroll
            for (int g = 0; g < 8; ++g) {
                va[g] = *(const half4*)(U + mt32(colA, g));
                vb[g] = *(const half4*)(U + mt32(colB, g));
            }
            int dArr[32];
            #pragma unroll
            for (int i4 = 0; i4 < 8; ++i4)
                *(int4*)(dArr + i4 * 4) = *(const int4*)(dW + i4 * 4);
            #pragma unroll
            for (int r = 0; r < 32; ++r) {
                int dd = dArr[r];
                float v0 = (float)va[r >> 2][r & 3];
                float v1 = (float)vb[r >> 2][r & 3];
                if (dd != prev) {   // wave-uniform branch
                    if (prev >= 0) {
                        unsafeAtomicAdd(&h[(size_t)prev * 128 + colA], carry0);
                        unsafeAtomicAdd(&h[(size_t)prev * 128 + colB], carry1);
                    }
                    prev = dd; carry0 = v0; carry1 = v1;
                } else { carry0 += v0; carry1 += v1; }
            }
        }
        pk = pkn;
        __builtin_amdgcn_sched_barrier(0);   // no cross-iteration load hoisting
    }
    if (prev >= 0) {
        unsafeAtomicAdd(&h[(size_t)prev * 128 + colA], carry0);
        unsafeAtomicAdd(&h[(size_t)prev * 128 + colB], carry1);
    }
}

// fused readout: hr = relu(h@Wr1+br1)·Wr2 + br2, out[gid] += hr  (per row)
__global__ __launch_bounds__(1024, 4) void readout_k(
        const float* __restrict__ X, int M,
        const float* __restrict__ W1, const float* __restrict__ b1,
        const float* __restrict__ Wr2, const float* __restrict__ br2,
        const int* __restrict__ gid, float* __restrict__ out) {
    __shared__ f16 W1T[128 * 136];
    __shared__ f16 xBuf[256 * 136];
    __shared__ float bias1[128];
    __shared__ float sWr2[128];
    int tid = threadIdx.x;

    stage_WT(W1, W1T, tid, 1024);
    if (tid < 128) { bias1[tid] = b1[tid]; sWr2[tid] = Wr2[tid]; }

    int r0 = blockIdx.x * 256;
    for (int it = 0; it < 8; ++it) {
        int row = it * 32 + (tid >> 5);
        int c4 = (tid & 31) * 4;
        int gr = r0 + row;
        floatx4 x = {0.0f, 0.0f, 0.0f, 0.0f};
        if (gr < M) x = *(const floatx4*)(X + (size_t)gr * 128 + c4);
        half4 xh;
        xh[0] = (f16)x[0]; xh[1] = (f16)x[1]; xh[2] = (f16)x[2]; xh[3] = (f16)x[3];
        *(half4*)(xBuf + row * 136 + c4) = xh;
    }
    __syncthreads();

    int lane = tid & 63, wv = tid >> 6;
    int R = wv * 16;
    int n16 = lane & 15, q = lane >> 4;

    half8 a[4];
    #pragma unroll
    for (int kk = 0; kk < 4; ++kk)
        a[kk] = *(const half8*)(xBuf + (R + n16) * 136 + kk * 32 + q * 8);

    floatx4 acc[8];
    #pragma unroll
    for (int f = 0; f < 8; ++f) {
        float bb = bias1[f * 16 + n16];
        acc[f] = (floatx4){bb, bb, bb, bb};
        #pragma unroll
        for (int kk = 0; kk < 4; ++kk) {
            half8 b = *(const half8*)(W1T + (f * 16 + n16) * 136 + kk * 32 + q * 8);
            acc[f] = __builtin_amdgcn_mfma_f32_16x16x32_f16(a[kk], b, acc[f], 0, 0, 0);
        }
    }

    float s[4];
    #pragma unroll
    for (int i = 0; i < 4; ++i) {
        float t = 0.0f;
        #pragma unroll
        for (int f = 0; f < 8; ++f)
            t += fmaxf(acc[f][i], 0.0f) * sWr2[f * 16 + n16];
        #pragma unroll
        for (int m = 1; m < 16; m <<= 1) t += __shfl_xor(t, m);
        s[i] = t;
    }

    if (n16 == 0) {
        float br2v = br2[0];
        float t = 0.0f; int g = -1;
        #pragma unroll
        for (int i = 0; i < 4; ++i) {
            int gr = r0 + R + q * 4 + i;
            if (gr < M) {
                int gi = gid[gr];
                float si = s[i] + br2v;
                if (gi == g) t += si;
                else { if (g >= 0) unsafeAtomicAdd(&out[g], t); g = gi; t = si; }
            }
        }
        if (g >= 0) unsafeAtomicAdd(&out[g], t);
    }
}

extern "C" void kernel_launch(void* const* d_in, const int* in_sizes, int n_in,
                              void* d_out, int out_size, void* d_ws, size_t ws_size,
                              hipStream_t stream) {
    (void)in_sizes; (void)n_in; (void)ws_size;
    const int*   node_types = (const int*)d_in[0];
    const int*   edge_types = (const int*)d_in[1];
    const int*   src        = (const int*)d_in[2];
    const int*   dst        = (const int*)d_in[3];
    const int*   graph_ids  = (const int*)d_in[4];
    const float* distances  = (const float*)d_in[5];
    const float* node_emb   = (const float*)d_in[7];
    const float* edge_emb   = (const float*)d_in[8];
    const float* Wn1 = (const float*)d_in[9];
    const float* bn1 = (const float*)d_in[10];
    const float* Wn2 = (const float*)d_in[11];
    const float* bn2 = (const float*)d_in[12];
    const float* We1 = (const float*)d_in[13];
    const float* be1 = (const float*)d_in[14];
    const float* We2 = (const float*)d_in[15];
    const float* be2 = (const float*)d_in[16];
    const float* Wc  = (const float*)d_in[17];
    const float* bc  = (const float*)d_in[18];
    const float* Wr1 = (const float*)d_in[19];
    const float* br1 = (const float*)d_in[20];
    const float* Wr2 = (const float*)d_in[21];
    const float* br2 = (const float*)d_in[22];

    char* w = (char*)d_ws;
    auto carve = [&](size_t bytes) { char* p = w; w += (bytes + 255) & ~(size_t)255; return p; };
    float* h        = (float*)carve((size_t)NNODES * 128 * 4);
    f16*   P        = (f16*)  carve((size_t)NNODES * 128 * 2);
    f16*   T        = (f16*)  carve((size_t)500 * 128 * 2);
    int*   rowStart = (int*)  carve((size_t)(NNODES + 1) * 4);
    int*   cnt      = (int*)  carve((size_t)NNODES * 4);
    int*   blockSum = (int*)  carve((size_t)64 * 4);
    uint4* packE    = (uint4*)carve((size_t)NEDGES * 16);

    float* out = (float*)d_out;
    const int NB1 = (NNODES + 1023) / 1024;   // 49

    init_k<<<(NNODES + 255) / 256, 256, 0, stream>>>(out, out_size, cnt);
    hist_k<<<NEDGES / 256, 256, 0, stream>>>(dst, cnt);
    scan1_k<<<NB1, 1024, 0, stream>>>(cnt, rowStart, blockSum);
    scan2_k<<<1, 64, 0, stream>>>(blockSum, NB1);
    scan3_k<<<NB1, 1024, 0, stream>>>(rowStart, blockSum, cnt);
    scatter_k<<<NEDGES / 256, 256, 0, stream>>>(src, edge_types, dst, distances,
                                                rowStart, cnt, packE);
    gather_h<<<(NNODES * 32 + 255) / 256, 256, 0, stream>>>(node_types, node_emb, h);

    for (int i = 0; i < 3; ++i) {
        mlp_combo<<<NB0 + 2, 1024, 0, stream>>>(
            h, Wn1 + (size_t)i * 128 * 128, bn1 + i * 128,
            Wn2 + (size_t)i * 128 * 128, bn2 + i * 128, P,
            edge_emb, We1 + (size_t)i * 158 * 128, be1 + i * 128, T);
        edge_kernel<<<256, 640, 0, stream>>>(
            packE, P, T,
            We1 + (size_t)i * 158 * 128,
            We2 + (size_t)i * 128 * 128, be2 + i * 128,
            Wc + (size_t)i * 128 * 128, bc + i * 128, h);
    }

    readout_k<<<(NNODES + 255) / 256, 1024, 0, stream>>>(
        h, NNODES, Wr1, br1, Wr2, br2, graph_ids, out);
}

// Round 7
// 701.588 us; speedup vs baseline: 1.3825x; 1.3825x over previous
//
#include <hip/hip_runtime.h>
#include <stdint.h>

#define NNODES 50000
#define NEDGES 800000
#define NGRAPH 100
#define NCHUNK32 (NEDGES / 32)   // 25000 32-edge chunks
#define NWAVES32 2048            // 256 blocks x 8 waves
#define NB0 196                  // mlp blocks for 50000 rows (256/block)

typedef _Float16 f16;
typedef __attribute__((ext_vector_type(8))) _Float16 half8;
typedef __attribute__((ext_vector_type(4))) _Float16 half4;
typedef __attribute__((ext_vector_type(4))) float floatx4;

// stage 128x128 fp32 row-major W[k][n] -> LDS WT[n][136 pad] fp16, float4 loads
__device__ __forceinline__ void stage_WT(const float* __restrict__ W, f16* WT,
                                         int tid, int nthr) {
    for (int idx = tid; idx < 128 * 32; idx += nthr) {
        int k = idx >> 5, n4 = (idx & 31) * 4;
        floatx4 v = *(const floatx4*)(W + k * 128 + n4);
        WT[(n4 + 0) * 136 + k] = (f16)v[0];
        WT[(n4 + 1) * 136 + k] = (f16)v[1];
        WT[(n4 + 2) * 136 + k] = (f16)v[2];
        WT[(n4 + 3) * 136 + k] = (f16)v[3];
    }
}

__device__ __forceinline__ float fast_tanh(float x) {
    x = fminf(fmaxf(x, -15.0f), 15.0f);
    float e2 = __expf(2.0f * x);
    return (e2 - 1.0f) * __builtin_amdgcn_rcpf(e2 + 1.0f);
}

// transposed-m for 32-edge chunks: column c owns f16 elements [c*32, c*32+32);
// 8 groups of 4 edges, rotated by (c>>1) so E-writes/F-reads spread bank-pairs
// evenly (16 distinct bank-pairs per instruction). Bijective per column.
__device__ __forceinline__ int mt32(int c, int g) {
    return c * 32 + ((((c >> 1) + g) & 7) << 2);
}

__global__ void init_k(float* out, int osz, int* cnt) {
    int i = blockIdx.x * 256 + threadIdx.x;
    if (i < osz) out[i] = 0.0f;
    if (i < NNODES) cnt[i] = 0;
}

__global__ void hist_k(const int* __restrict__ dst, int* __restrict__ cnt) {
    int e = blockIdx.x * 256 + threadIdx.x;
    if (e < NEDGES) atomicAdd(&cnt[dst[e]], 1);
}

__global__ __launch_bounds__(1024) void scan1_k(const int* __restrict__ cnt,
                                                int* __restrict__ rowStart,
                                                int* __restrict__ blockSum) {
    __shared__ int buf[1024];
    int tid = threadIdx.x;
    int i = blockIdx.x * 1024 + tid;
    int v = (i < NNODES) ? cnt[i] : 0;
    buf[tid] = v;
    __syncthreads();
    for (int off = 1; off < 1024; off <<= 1) {
        int t = (tid >= off) ? buf[tid - off] : 0;
        __syncthreads();
        buf[tid] += t;
        __syncthreads();
    }
    if (i < NNODES) rowStart[i] = buf[tid] - v;
    if (tid == 1023) blockSum[blockIdx.x] = buf[1023];
}

__global__ void scan2_k(int* __restrict__ blockSum, int nb) {
    if (threadIdx.x == 0) {
        int run = 0;
        for (int b = 0; b < nb; ++b) { int s = blockSum[b]; blockSum[b] = run; run += s; }
    }
}

__global__ __launch_bounds__(1024) void scan3_k(int* __restrict__ rowStart,
                                                const int* __restrict__ blockSum,
                                                int* __restrict__ cnt) {
    int i = blockIdx.x * 1024 + threadIdx.x;
    if (i < NNODES) { rowStart[i] += blockSum[blockIdx.x]; cnt[i] = 0; }
    if (i == 0) rowStart[NNODES] = NEDGES;
}

__global__ void scatter_k(const int* __restrict__ src, const int* __restrict__ et,
                          const int* __restrict__ dst, const float* __restrict__ dist,
                          const int* __restrict__ rowStart, int* __restrict__ cnt,
                          uint4* __restrict__ packE) {
    int e = blockIdx.x * 256 + threadIdx.x;
    if (e >= NEDGES) return;
    int d = dst[e];
    int pos = rowStart[d] + atomicAdd(&cnt[d], 1);
    uint4 pk;
    pk.x = (unsigned)src[e];
    pk.y = (unsigned)et[e];
    pk.z = (unsigned)d;
    pk.w = __float_as_uint(dist[e]);
    packE[pos] = pk;
}

__global__ void gather_h(const int* __restrict__ nt, const float* __restrict__ emb,
                         float* __restrict__ h) {
    int i = blockIdx.x * 256 + threadIdx.x;
    int row = i >> 5, c4 = (i & 31) * 4;
    if (row < NNODES)
        *(floatx4*)(h + row * 128 + c4) = *(const floatx4*)(emb + nt[row] * 128 + c4);
}

// ---------------------------------------------------------------------------
// Fused node-MLP + edge-type-table kernel (one launch per layer):
//   blocks [0, NB0)      : P = relu(h@Wn1+bn1)@Wn2+bn2      (50000 rows)
//   blocks [NB0, NB0+2)  : T = edge_emb@We1[:128]+be1        (500 rows)
// ---------------------------------------------------------------------------
__global__ __launch_bounds__(1024, 4) void mlp_combo(
        const float* __restrict__ Xh,
        const float* __restrict__ W1, const float* __restrict__ b1,
        const float* __restrict__ W2, const float* __restrict__ b2,
        f16* __restrict__ OutP,
        const float* __restrict__ Xe,
        const float* __restrict__ We1, const float* __restrict__ be1,
        f16* __restrict__ OutT) {
    __shared__ f16 W1T[128 * 136];
    __shared__ f16 W2T[128 * 136];
    __shared__ f16 xBuf[256 * 136];
    __shared__ float bias1[128];
    __shared__ float bias2[128];
    int tid = threadIdx.x;
    bool mode2 = blockIdx.x >= NB0;

    const float* X  = mode2 ? Xe : Xh;
    const float* Wa = mode2 ? We1 : W1;
    const float* ba = mode2 ? be1 : b1;
    f16* Out        = mode2 ? OutT : OutP;
    int  M          = mode2 ? 500 : NNODES;
    int  r0         = (mode2 ? (blockIdx.x - NB0) : blockIdx.x) * 256;

    stage_WT(Wa, W1T, tid, 1024);
    if (!mode2) stage_WT(W2, W2T, tid, 1024);
    if (tid < 128) { bias1[tid] = ba[tid]; bias2[tid] = mode2 ? 0.0f : b2[tid]; }

    for (int it = 0; it < 8; ++it) {
        int row = it * 32 + (tid >> 5);
        int c4 = (tid & 31) * 4;
        int gr = r0 + row;
        floatx4 x = {0.0f, 0.0f, 0.0f, 0.0f};
        if (gr < M) x = *(const floatx4*)(X + (size_t)gr * 128 + c4);
        half4 xh;
        xh[0] = (f16)x[0]; xh[1] = (f16)x[1]; xh[2] = (f16)x[2]; xh[3] = (f16)x[3];
        *(half4*)(xBuf + row * 136 + c4) = xh;
    }
    __syncthreads();

    int lane = tid & 63, wv = tid >> 6;
    int R = wv * 16;
    int n16 = lane & 15, q = lane >> 4;
    int gr = r0 + R + n16;

    half8 a[4];
    #pragma unroll
    for (int kk = 0; kk < 4; ++kk)
        a[kk] = *(const half8*)(xBuf + (R + n16) * 136 + kk * 32 + q * 8);

    #pragma unroll
    for (int f = 0; f < 8; ++f) {
        floatx4 acc = *(const floatx4*)(bias1 + f * 16 + q * 4);
        #pragma unroll
        for (int kk = 0; kk < 4; ++kk) {
            half8 aw = *(const half8*)(W1T + (f * 16 + n16) * 136 + kk * 32 + q * 8);
            acc = __builtin_amdgcn_mfma_f32_16x16x32_f16(aw, a[kk], acc, 0, 0, 0);
        }
        if (!mode2) {
            half4 y;
            #pragma unroll
            for (int i = 0; i < 4; ++i) y[i] = (f16)fmaxf(acc[i], 0.0f);
            *(half4*)(xBuf + (R + n16) * 136 + f * 16 + q * 4) = y;
        } else {
            half4 o;
            #pragma unroll
            for (int i = 0; i < 4; ++i) o[i] = (f16)acc[i];
            if (gr < M) *(half4*)(Out + (size_t)gr * 128 + f * 16 + q * 4) = o;
        }
    }

    if (!mode2) {
        #pragma unroll
        for (int kk = 0; kk < 4; ++kk)
            a[kk] = *(const half8*)(xBuf + (R + n16) * 136 + kk * 32 + q * 8);
        #pragma unroll
        for (int f = 0; f < 8; ++f) {
            floatx4 acc = *(const floatx4*)(bias2 + f * 16 + q * 4);
            #pragma unroll
            for (int kk = 0; kk < 4; ++kk) {
                half8 aw = *(const half8*)(W2T + (f * 16 + n16) * 136 + kk * 32 + q * 8);
                acc = __builtin_amdgcn_mfma_f32_16x16x32_f16(aw, a[kk], acc, 0, 0, 0);
            }
            half4 o;
            #pragma unroll
            for (int i = 0; i < 4; ++i) o[i] = (f16)acc[i];
            if (gr < M) *(half4*)(Out + (size_t)gr * 128 + f * 16 + q * 4) = o;
        }
    }
}

// ---------------------------------------------------------------------------
// Barrier-free edge kernel, 32-edge chunks, 8 waves/block (R5 base — the
// verified session best: 139.0 us, FETCH 80.6 MB, conflicts 1.99e7) plus a
// 1-DEEP T PREFETCH: next chunk's T rows load into short-lived NAMED uint4
// regs after phase C (addresses from pkn), covered by E+F latency; next
// iteration's phase A writes regs to LDS with no global drain on the
// critical path. This is the pA0..pB3 pattern (named regs across phases,
// proven held in R5), NOT the loop-invariant-array pattern that spilled in
// R3'/R6 (compiler refuses to hold invariant arrays across the fenced loop;
// scratch stream thrashes the at-capacity L2 -> FETCH 230-249 MB).
// T is 128 KB L2-resident: in-flight T loads crossing the iteration fence
// add no HBM traffic. P stays strictly fenced (R8/R10: hoisted P gathers =
// FETCH 223 MB). sbe2/sbc stay in LDS (R3'). W1rT stays in LDS (R6).
// Tripwire: FETCH must stay ~80.6 MB / WRITE ~26 MB, VGPR ~155 no-spill.
// ---------------------------------------------------------------------------
__global__ __launch_bounds__(512, 2) void edge_kernel(
        const uint4* __restrict__ packE,
        const f16* __restrict__ P, const f16* __restrict__ T,
        const float* __restrict__ We1,
        const float* __restrict__ We2, const float* __restrict__ be2,
        const float* __restrict__ Wc,  const float* __restrict__ bc,
        float* __restrict__ h) {
    __shared__ f16 W2T[128 * 136];       // 34816 B
    __shared__ f16 WcT[128 * 136];       // 34816 B
    __shared__ f16 W1rT[128 * 40];       // 10240 B
    __shared__ f16 Uall[8 * 4352];       // 69632 B : per-wave 32x136 (T/u/ep) then mT
    __shared__ float sbe2[128], sbc[128];
    __shared__ int dstW[8][32];
    // total 151552 B -> 1 block/CU, 8 waves

    int tid = threadIdx.x;
    stage_WT(We2, W2T, tid, 512);
    stage_WT(Wc,  WcT, tid, 512);
    for (int idx = tid; idx < 128 * 32; idx += 512) {
        int n = idx >> 5, kr = idx & 31;
        W1rT[n * 40 + kr] = (kr < 30) ? (f16)We1[(128 + kr) * 128 + n] : (f16)0.0f;
    }
    if (tid < 128) { sbe2[tid] = be2[tid]; sbc[tid] = bc[tid]; }
    __syncthreads();    // weights ready; the ONLY block barrier

    int lane = tid & 63, wv = tid >> 6;      // wv 0..7
    f16* U = Uall + wv * 4352;
    int* dW = dstW[wv];
    int n16 = lane & 15, q = lane >> 4;
    const float invgap = 29.0f / 10.0f;
    int colA = lane, colB = lane + 64;
    int tsub = lane & 3, trow = lane >> 2;

    float sbcv[8];
    #pragma unroll
    for (int f = 0; f < 8; ++f) sbcv[f] = sbc[f * 16 + n16];

    // balanced stripe: 25000 chunks over 2048 waves (12 or 13 each)
    int wgid = blockIdx.x * 8 + wv;
    int extra = wgid < 424 ? wgid : 424;
    int c0 = wgid * 12 + extra;
    int c1 = c0 + 12 + (wgid < 424 ? 1 : 0);

    float carry0 = 0.0f, carry1 = 0.0f;
    int prev = -1;

    // prologue: pk for chunk c0 (32 records) + T prefetch for c0
    uint4 pk = {0u, 0u, 0u, 0u};
    if (lane < 32) pk = packE[(size_t)c0 * 32 + lane];
    uint4 tA0, tA1, tA2, tA3, tB0, tB1, tB2, tB3;
    {
        int etyA = __shfl((int)pk.y, trow);
        int etyB = __shfl((int)pk.y, trow + 16);
        const uint4* Tp0 = (const uint4*)(T + (size_t)etyA * 128 + tsub * 32);
        const uint4* Tp1 = (const uint4*)(T + (size_t)etyB * 128 + tsub * 32);
        tA0 = Tp0[0]; tA1 = Tp0[1]; tA2 = Tp0[2]; tA3 = Tp0[3];
        tB0 = Tp1[0]; tB1 = Tp1[1]; tB2 = Tp1[2]; tB3 = Tp1[3];
    }

    for (int ch = c0; ch < c1; ++ch) {
        bool hasNext = (ch + 1 < c1);
        // ---- distribute current records -----------------------------------
        int   srcv0 = __shfl((int)pk.x, n16);
        int   srcv1 = __shfl((int)pk.x, n16 + 16);
        float d0    = __shfl(__uint_as_float(pk.w), n16);
        float d1    = __shfl(__uint_as_float(pk.w), n16 + 16);
        if (lane < 32) dW[lane] = (int)pk.z;

        // ---- phase A: prefetched T regs -> LDS (no global drain) ----------
        {
            uint4* u0 = (uint4*)(U + trow * 136 + tsub * 32);
            uint4* u1 = (uint4*)(U + (16 + trow) * 136 + tsub * 32);
            u0[0] = tA0; u0[1] = tA1; u0[2] = tA2; u0[3] = tA3;
            u1[0] = tB0; u1[1] = tB1; u1[2] = tB2; u1[3] = tB3;
        }
        __builtin_amdgcn_sched_barrier(0);   // T writes placed before P issues

        // ---- NOW issue P loads ---------------------------------------------
        half8 pA0, pA1, pA2, pA3, pB0, pB1, pB2, pB3;
        {
            const f16* Pr0 = P + (size_t)srcv0 * 128 + q * 8;
            const f16* Pr1 = P + (size_t)srcv1 * 128 + q * 8;
            pA0 = *(const half8*)(Pr0);      pA1 = *(const half8*)(Pr0 + 32);
            pA2 = *(const half8*)(Pr0 + 64); pA3 = *(const half8*)(Pr0 + 96);
            pB0 = *(const half8*)(Pr1);      pB1 = *(const half8*)(Pr1 + 32);
            pB2 = *(const half8*)(Pr1 + 64); pB3 = *(const half8*)(Pr1 + 96);
        }
        uint4 pkn = {0u, 0u, 0u, 0u};
        if (hasNext && lane < 32) pkn = packE[(size_t)(ch + 1) * 32 + lane];

        // ---- rbf in regs (VALU overlaps P latency) ------------------------
        half8 ar0, ar1;
        #pragma unroll
        for (int j = 0; j < 8; ++j) {
            int k = q * 8 + j;
            float c = (float)k * (10.0f / 29.0f);
            float df0 = d0 - c, df1 = d1 - c;
            ar0[j] = (f16)((k < 30) ? __expf(-df0 * df0 * invgap) : 0.0f);
            ar1[j] = (f16)((k < 30) ? __expf(-df1 * df1 * invgap) : 0.0f);
        }

        // ---- B: u^T = relu(W1r^T @ rbf^T + T^T); 1 weight read, 2 MFMAs ---
        #pragma unroll
        for (int f = 0; f < 8; ++f) {
            half8 aw = *(const half8*)(W1rT + (f * 16 + n16) * 40 + q * 8);
            f16* up0 = U + n16 * 136 + f * 16 + q * 4;
            f16* up1 = U + (16 + n16) * 136 + f * 16 + q * 4;
            half4 tv0 = *(const half4*)up0;
            half4 tv1 = *(const half4*)up1;
            floatx4 c40 = {(float)tv0[0], (float)tv0[1], (float)tv0[2], (float)tv0[3]};
            floatx4 c41 = {(float)tv1[0], (float)tv1[1], (float)tv1[2], (float)tv1[3]};
            c40 = __builtin_amdgcn_mfma_f32_16x16x32_f16(aw, ar0, c40, 0, 0, 0);
            c41 = __builtin_amdgcn_mfma_f32_16x16x32_f16(aw, ar1, c41, 0, 0, 0);
            half4 uv0, uv1;
            #pragma unroll
            for (int i = 0; i < 4; ++i) {
                uv0[i] = (f16)fmaxf(c40[i], 0.0f);
                uv1[i] = (f16)fmaxf(c41[i], 0.0f);
            }
            *(half4*)up0 = uv0;
            *(half4*)up1 = uv1;
        }

        // ---- C: ep^T = W2^T @ u^T + be2; 1 weight read, 2 MFMAs -----------
        half8 a20[4], a21[4];
        #pragma unroll
        for (int kk = 0; kk < 4; ++kk) {
            a20[kk] = *(const half8*)(U + n16 * 136 + kk * 32 + q * 8);
            a21[kk] = *(const half8*)(U + (16 + n16) * 136 + kk * 32 + q * 8);
        }
        #pragma unroll
        for (int f = 0; f < 8; ++f) {
            floatx4 acc0 = *(const floatx4*)(sbe2 + f * 16 + q * 4);
            floatx4 acc1 = acc0;
            #pragma unroll
            for (int kk = 0; kk < 4; ++kk) {
                half8 aw = *(const half8*)(W2T + (f * 16 + n16) * 136 + kk * 32 + q * 8);
                acc0 = __builtin_amdgcn_mfma_f32_16x16x32_f16(aw, a20[kk], acc0, 0, 0, 0);
                acc1 = __builtin_amdgcn_mfma_f32_16x16x32_f16(aw, a21[kk], acc1, 0, 0, 0);
            }
            half4 ev0, ev1;
            #pragma unroll
            for (int i = 0; i < 4; ++i) { ev0[i] = (f16)acc0[i]; ev1[i] = (f16)acc1[i]; }
            *(half4*)(U + n16 * 136 + f * 16 + q * 4) = ev0;
            *(half4*)(U + (16 + n16) * 136 + f * 16 + q * 4) = ev1;
        }

        // ---- T PREFETCH for ch+1 (covered by E+F; T is L2-resident) -------
        if (hasNext) {
            int etyA = __shfl((int)pkn.y, trow);
            int etyB = __shfl((int)pkn.y, trow + 16);
            const uint4* Tp0 = (const uint4*)(T + (size_t)etyA * 128 + tsub * 32);
            const uint4* Tp1 = (const uint4*)(T + (size_t)etyB * 128 + tsub * 32);
            tA0 = Tp0[0]; tA1 = Tp0[1]; tA2 = Tp0[2]; tA3 = Tp0[3];
            tB0 = Tp1[0]; tB1 = Tp1[1]; tB2 = Tp1[2]; tB3 = Tp1[3];
        }

        // ---- E: m = tanh((P ⊙ ep) @ Wc + bc); 1 weight read, 2 MFMAs ------
        {
            half8 e00 = *(const half8*)(U + n16 * 136 + 0 * 32 + q * 8);
            half8 e01 = *(const half8*)(U + n16 * 136 + 1 * 32 + q * 8);
            half8 e02 = *(const half8*)(U + n16 * 136 + 2 * 32 + q * 8);
            half8 e03 = *(const half8*)(U + n16 * 136 + 3 * 32 + q * 8);
            half8 e10 = *(const half8*)(U + (16 + n16) * 136 + 0 * 32 + q * 8);
            half8 e11 = *(const half8*)(U + (16 + n16) * 136 + 1 * 32 + q * 8);
            half8 e12 = *(const half8*)(U + (16 + n16) * 136 + 2 * 32 + q * 8);
            half8 e13 = *(const half8*)(U + (16 + n16) * 136 + 3 * 32 + q * 8);
            a20[0] = e00 * pA0; a20[1] = e01 * pA1; a20[2] = e02 * pA2; a20[3] = e03 * pA3;
            a21[0] = e10 * pB0; a21[1] = e11 * pB1; a21[2] = e12 * pB2; a21[3] = e13 * pB3;
        }
        #pragma unroll
        for (int f = 0; f < 8; ++f) {
            float bb = sbcv[f];
            floatx4 acc0 = {bb, bb, bb, bb};
            floatx4 acc1 = {bb, bb, bb, bb};
            #pragma unroll
            for (int kk = 0; kk < 4; ++kk) {
                half8 b = *(const half8*)(WcT + (f * 16 + n16) * 136 + kk * 32 + q * 8);
                acc0 = __builtin_amdgcn_mfma_f32_16x16x32_f16(a20[kk], b, acc0, 0, 0, 0);
                acc1 = __builtin_amdgcn_mfma_f32_16x16x32_f16(a21[kk], b, acc1, 0, 0, 0);
            }
            int c = f * 16 + n16;
            half4 mv0, mv1;
            #pragma unroll
            for (int i = 0; i < 4; ++i) {
                mv0[i] = (f16)fast_tanh(acc0[i]);
                mv1[i] = (f16)fast_tanh(acc1[i]);
            }
            *(half4*)(U + mt32(c, q))     = mv0;   // edges q*4..q*4+3
            *(half4*)(U + mt32(c, 4 + q)) = mv1;   // edges 16+q*4..16+q*4+3
        }

        // ---- F: per-col segment reduce over 32 rows with carry ------------
        {
            half4 va[8], vb[8];
            #pragma unroll
            for (int g = 0; g < 8; ++g) {
                va[g] = *(const half4*)(U + mt32(colA, g));
                vb[g] = *(const half4*)(U + mt32(colB, g));
            }
            int dArr[32];
            #pragma unroll
            for (int i4 = 0; i4 < 8; ++i4)
                *(int4*)(dArr + i4 * 4) = *(const int4*)(dW + i4 * 4);
            #pragma unroll
            for (int r = 0; r < 32; ++r) {
                int dd = dArr[r];
                float v0 = (float)va[r >> 2][r & 3];
                float v1 = (float)vb[r >> 2][r & 3];
                if (dd != prev) {   // wave-uniform branch
                    if (prev >= 0) {
                        unsafeAtomicAdd(&h[(size_t)prev * 128 + colA], carry0);
                        unsafeAtomicAdd(&h[(size_t)prev * 128 + colB], carry1);
                    }
                    prev = dd; carry0 = v0; carry1 = v1;
                } else { carry0 += v0; carry1 += v1; }
            }
        }
        pk = pkn;
        __builtin_amdgcn_sched_barrier(0);   // no cross-iteration P hoisting
    }
    if (prev >= 0) {
        unsafeAtomicAdd(&h[(size_t)prev * 128 + colA], carry0);
        unsafeAtomicAdd(&h[(size_t)prev * 128 + colB], carry1);
    }
}

// fused readout: hr = relu(h@Wr1+br1)·Wr2 + br2, out[gid] += hr  (per row)
__global__ __launch_bounds__(1024, 4) void readout_k(
        const float* __restrict__ X, int M,
        const float* __restrict__ W1, const float* __restrict__ b1,
        const float* __restrict__ Wr2, const float* __restrict__ br2,
        const int* __restrict__ gid, float* __restrict__ out) {
    __shared__ f16 W1T[128 * 136];
    __shared__ f16 xBuf[256 * 136];
    __shared__ float bias1[128];
    __shared__ float sWr2[128];
    int tid = threadIdx.x;

    stage_WT(W1, W1T, tid, 1024);
    if (tid < 128) { bias1[tid] = b1[tid]; sWr2[tid] = Wr2[tid]; }

    int r0 = blockIdx.x * 256;
    for (int it = 0; it < 8; ++it) {
        int row = it * 32 + (tid >> 5);
        int c4 = (tid & 31) * 4;
        int gr = r0 + row;
        floatx4 x = {0.0f, 0.0f, 0.0f, 0.0f};
        if (gr < M) x = *(const floatx4*)(X + (size_t)gr * 128 + c4);
        half4 xh;
        xh[0] = (f16)x[0]; xh[1] = (f16)x[1]; xh[2] = (f16)x[2]; xh[3] = (f16)x[3];
        *(half4*)(xBuf + row * 136 + c4) = xh;
    }
    __syncthreads();

    int lane = tid & 63, wv = tid >> 6;
    int R = wv * 16;
    int n16 = lane & 15, q = lane >> 4;

    half8 a[4];
    #pragma unroll
    for (int kk = 0; kk < 4; ++kk)
        a[kk] = *(const half8*)(xBuf + (R + n16) * 136 + kk * 32 + q * 8);

    floatx4 acc[8];
    #pragma unroll
    for (int f = 0; f < 8; ++f) {
        float bb = bias1[f * 16 + n16];
        acc[f] = (floatx4){bb, bb, bb, bb};
        #pragma unroll
        for (int kk = 0; kk < 4; ++kk) {
            half8 b = *(const half8*)(W1T + (f * 16 + n16) * 136 + kk * 32 + q * 8);
            acc[f] = __builtin_amdgcn_mfma_f32_16x16x32_f16(a[kk], b, acc[f], 0, 0, 0);
        }
    }

    float s[4];
    #pragma unroll
    for (int i = 0; i < 4; ++i) {
        float t = 0.0f;
        #pragma unroll
        for (int f = 0; f < 8; ++f)
            t += fmaxf(acc[f][i], 0.0f) * sWr2[f * 16 + n16];
        #pragma unroll
        for (int m = 1; m < 16; m <<= 1) t += __shfl_xor(t, m);
        s[i] = t;
    }

    if (n16 == 0) {
        float br2v = br2[0];
        float t = 0.0f; int g = -1;
        #pragma unroll
        for (int i = 0; i < 4; ++i) {
            int gr = r0 + R + q * 4 + i;
            if (gr < M) {
                int gi = gid[gr];
                float si = s[i] + br2v;
                if (gi == g) t += si;
                else { if (g >= 0) unsafeAtomicAdd(&out[g], t); g = gi; t = si; }
            }
        }
        if (g >= 0) unsafeAtomicAdd(&out[g], t);
    }
}

extern "C" void kernel_launch(void* const* d_in, const int* in_sizes, int n_in,
                              void* d_out, int out_size, void* d_ws, size_t ws_size,
                              hipStream_t stream) {
    (void)in_sizes; (void)n_in; (void)ws_size;
    const int*   node_types = (const int*)d_in[0];
    const int*   edge_types = (const int*)d_in[1];
    const int*   src        = (const int*)d_in[2];
    const int*   dst        = (const int*)d_in[3];
    const int*   graph_ids  = (const int*)d_in[4];
    const float* distances  = (const float*)d_in[5];
    const float* node_emb   = (const float*)d_in[7];
    const float* edge_emb   = (const float*)d_in[8];
    const float* Wn1 = (const float*)d_in[9];
    const float* bn1 = (const float*)d_in[10];
    const float* Wn2 = (const float*)d_in[11];
    const float* bn2 = (const float*)d_in[12];
    const float* We1 = (const float*)d_in[13];
    const float* be1 = (const float*)d_in[14];
    const float* We2 = (const float*)d_in[15];
    const float* be2 = (const float*)d_in[16];
    const float* Wc  = (const float*)d_in[17];
    const float* bc  = (const float*)d_in[18];
    const float* Wr1 = (const float*)d_in[19];
    const float* br1 = (const float*)d_in[20];
    const float* Wr2 = (const float*)d_in[21];
    const float* br2 = (const float*)d_in[22];

    char* w = (char*)d_ws;
    auto carve = [&](size_t bytes) { char* p = w; w += (bytes + 255) & ~(size_t)255; return p; };
    float* h        = (float*)carve((size_t)NNODES * 128 * 4);
    f16*   P        = (f16*)  carve((size_t)NNODES * 128 * 2);
    f16*   T        = (f16*)  carve((size_t)500 * 128 * 2);
    int*   rowStart = (int*)  carve((size_t)(NNODES + 1) * 4);
    int*   cnt      = (int*)  carve((size_t)NNODES * 4);
    int*   blockSum = (int*)  carve((size_t)64 * 4);
    uint4* packE    = (uint4*)carve((size_t)NEDGES * 16);

    float* out = (float*)d_out;
    const int NB1 = (NNODES + 1023) / 1024;   // 49

    init_k<<<(NNODES + 255) / 256, 256, 0, stream>>>(out, out_size, cnt);
    hist_k<<<NEDGES / 256, 256, 0, stream>>>(dst, cnt);
    scan1_k<<<NB1, 1024, 0, stream>>>(cnt, rowStart, blockSum);
    scan2_k<<<1, 64, 0, stream>>>(blockSum, NB1);
    scan3_k<<<NB1, 1024, 0, stream>>>(rowStart, blockSum, cnt);
    scatter_k<<<NEDGES / 256, 256, 0, stream>>>(src, edge_types, dst, distances,
                                                rowStart, cnt, packE);
    gather_h<<<(NNODES * 32 + 255) / 256, 256, 0, stream>>>(node_types, node_emb, h);

    for (int i = 0; i < 3; ++i) {
        mlp_combo<<<NB0 + 2, 1024, 0, stream>>>(
            h, Wn1 + (size_t)i * 128 * 128, bn1 + i * 128,
            Wn2 + (size_t)i * 128 * 128, bn2 + i * 128, P,
            edge_emb, We1 + (size_t)i * 158 * 128, be1 + i * 128, T);
        edge_kernel<<<256, 512, 0, stream>>>(
            packE, P, T,
            We1 + (size_t)i * 158 * 128,
            We2 + (size_t)i * 128 * 128, be2 + i * 128,
            Wc + (size_t)i * 128 * 128, bc + i * 128, h);
    }

    readout_k<<<(NNODES + 255) / 256, 1024, 0, stream>>>(
        h, NNODES, Wr1, br1, Wr2, br2, graph_ids, out);
}

// Round 8
// 675.744 us; speedup vs baseline: 1.4354x; 1.0382x over previous
//
#include <hip/hip_runtime.h>
#include <stdint.h>

#define NNODES 50000
#define NEDGES 800000
#define NGRAPH 100
#define NCHUNK32 (NEDGES / 32)   // 25000 32-edge chunks
#define NWAVES32 2048            // 256 blocks x 8 waves
#define NB0 196                  // mlp blocks for 50000 rows (256/block)

typedef _Float16 f16;
typedef __attribute__((ext_vector_type(8))) _Float16 half8;
typedef __attribute__((ext_vector_type(4))) _Float16 half4;
typedef __attribute__((ext_vector_type(4))) float floatx4;

// stage 128x128 fp32 row-major W[k][n] -> LDS WT[n][136 pad] fp16, float4 loads
__device__ __forceinline__ void stage_WT(const float* __restrict__ W, f16* WT,
                                         int tid, int nthr) {
    for (int idx = tid; idx < 128 * 32; idx += nthr) {
        int k = idx >> 5, n4 = (idx & 31) * 4;
        floatx4 v = *(const floatx4*)(W + k * 128 + n4);
        WT[(n4 + 0) * 136 + k] = (f16)v[0];
        WT[(n4 + 1) * 136 + k] = (f16)v[1];
        WT[(n4 + 2) * 136 + k] = (f16)v[2];
        WT[(n4 + 3) * 136 + k] = (f16)v[3];
    }
}

__device__ __forceinline__ float fast_tanh(float x) {
    x = fminf(fmaxf(x, -15.0f), 15.0f);
    float e2 = __expf(2.0f * x);
    return (e2 - 1.0f) * __builtin_amdgcn_rcpf(e2 + 1.0f);
}

// transposed-m for 32-edge chunks: column c owns f16 elements [c*32, c*32+32);
// 8 groups of 4 edges, rotated by (c>>1) so E-writes/F-reads spread bank-pairs
// evenly (16 distinct bank-pairs per instruction). Bijective per column.
__device__ __forceinline__ int mt32(int c, int g) {
    return c * 32 + ((((c >> 1) + g) & 7) << 2);
}

__global__ void init_k(float* out, int osz, int* cnt) {
    int i = blockIdx.x * 256 + threadIdx.x;
    if (i < osz) out[i] = 0.0f;
    if (i < NNODES) cnt[i] = 0;
}

__global__ void hist_k(const int* __restrict__ dst, int* __restrict__ cnt) {
    int e = blockIdx.x * 256 + threadIdx.x;
    if (e < NEDGES) atomicAdd(&cnt[dst[e]], 1);
}

__global__ __launch_bounds__(1024) void scan1_k(const int* __restrict__ cnt,
                                                int* __restrict__ rowStart,
                                                int* __restrict__ blockSum) {
    __shared__ int buf[1024];
    int tid = threadIdx.x;
    int i = blockIdx.x * 1024 + tid;
    int v = (i < NNODES) ? cnt[i] : 0;
    buf[tid] = v;
    __syncthreads();
    for (int off = 1; off < 1024; off <<= 1) {
        int t = (tid >= off) ? buf[tid - off] : 0;
        __syncthreads();
        buf[tid] += t;
        __syncthreads();
    }
    if (i < NNODES) rowStart[i] = buf[tid] - v;
    if (tid == 1023) blockSum[blockIdx.x] = buf[1023];
}

__global__ void scan2_k(int* __restrict__ blockSum, int nb) {
    if (threadIdx.x == 0) {
        int run = 0;
        for (int b = 0; b < nb; ++b) { int s = blockSum[b]; blockSum[b] = run; run += s; }
    }
}

__global__ __launch_bounds__(1024) void scan3_k(int* __restrict__ rowStart,
                                                const int* __restrict__ blockSum,
                                                int* __restrict__ cnt) {
    int i = blockIdx.x * 1024 + threadIdx.x;
    if (i < NNODES) { rowStart[i] += blockSum[blockIdx.x]; cnt[i] = 0; }
    if (i == 0) rowStart[NNODES] = NEDGES;
}

__global__ void scatter_k(const int* __restrict__ src, const int* __restrict__ et,
                          const int* __restrict__ dst, const float* __restrict__ dist,
                          const int* __restrict__ rowStart, int* __restrict__ cnt,
                          uint4* __restrict__ packE) {
    int e = blockIdx.x * 256 + threadIdx.x;
    if (e >= NEDGES) return;
    int d = dst[e];
    int pos = rowStart[d] + atomicAdd(&cnt[d], 1);
    uint4 pk;
    pk.x = (unsigned)src[e];
    pk.y = (unsigned)et[e];
    pk.z = (unsigned)d;
    pk.w = __float_as_uint(dist[e]);
    packE[pos] = pk;
}

__global__ void gather_h(const int* __restrict__ nt, const float* __restrict__ emb,
                         float* __restrict__ h) {
    int i = blockIdx.x * 256 + threadIdx.x;
    int row = i >> 5, c4 = (i & 31) * 4;
    if (row < NNODES)
        *(floatx4*)(h + row * 128 + c4) = *(const floatx4*)(emb + nt[row] * 128 + c4);
}

// ---------------------------------------------------------------------------
// Fused node-MLP + edge-type-table kernel (one launch per layer):
//   blocks [0, NB0)      : P = relu(h@Wn1+bn1)@Wn2+bn2      (50000 rows)
//   blocks [NB0, NB0+2)  : T = edge_emb@We1[:128]+be1        (500 rows)
// ---------------------------------------------------------------------------
__global__ __launch_bounds__(1024, 4) void mlp_combo(
        const float* __restrict__ Xh,
        const float* __restrict__ W1, const float* __restrict__ b1,
        const float* __restrict__ W2, const float* __restrict__ b2,
        f16* __restrict__ OutP,
        const float* __restrict__ Xe,
        const float* __restrict__ We1, const float* __restrict__ be1,
        f16* __restrict__ OutT) {
    __shared__ f16 W1T[128 * 136];
    __shared__ f16 W2T[128 * 136];
    __shared__ f16 xBuf[256 * 136];
    __shared__ float bias1[128];
    __shared__ float bias2[128];
    int tid = threadIdx.x;
    bool mode2 = blockIdx.x >= NB0;

    const float* X  = mode2 ? Xe : Xh;
    const float* Wa = mode2 ? We1 : W1;
    const float* ba = mode2 ? be1 : b1;
    f16* Out        = mode2 ? OutT : OutP;
    int  M          = mode2 ? 500 : NNODES;
    int  r0         = (mode2 ? (blockIdx.x - NB0) : blockIdx.x) * 256;

    stage_WT(Wa, W1T, tid, 1024);
    if (!mode2) stage_WT(W2, W2T, tid, 1024);
    if (tid < 128) { bias1[tid] = ba[tid]; bias2[tid] = mode2 ? 0.0f : b2[tid]; }

    for (int it = 0; it < 8; ++it) {
        int row = it * 32 + (tid >> 5);
        int c4 = (tid & 31) * 4;
        int gr = r0 + row;
        floatx4 x = {0.0f, 0.0f, 0.0f, 0.0f};
        if (gr < M) x = *(const floatx4*)(X + (size_t)gr * 128 + c4);
        half4 xh;
        xh[0] = (f16)x[0]; xh[1] = (f16)x[1]; xh[2] = (f16)x[2]; xh[3] = (f16)x[3];
        *(half4*)(xBuf + row * 136 + c4) = xh;
    }
    __syncthreads();

    int lane = tid & 63, wv = tid >> 6;
    int R = wv * 16;
    int n16 = lane & 15, q = lane >> 4;
    int gr = r0 + R + n16;

    half8 a[4];
    #pragma unroll
    for (int kk = 0; kk < 4; ++kk)
        a[kk] = *(const half8*)(xBuf + (R + n16) * 136 + kk * 32 + q * 8);

    #pragma unroll
    for (int f = 0; f < 8; ++f) {
        floatx4 acc = *(const floatx4*)(bias1 + f * 16 + q * 4);
        #pragma unroll
        for (int kk = 0; kk < 4; ++kk) {
            half8 aw = *(const half8*)(W1T + (f * 16 + n16) * 136 + kk * 32 + q * 8);
            acc = __builtin_amdgcn_mfma_f32_16x16x32_f16(aw, a[kk], acc, 0, 0, 0);
        }
        if (!mode2) {
            half4 y;
            #pragma unroll
            for (int i = 0; i < 4; ++i) y[i] = (f16)fmaxf(acc[i], 0.0f);
            *(half4*)(xBuf + (R + n16) * 136 + f * 16 + q * 4) = y;
        } else {
            half4 o;
            #pragma unroll
            for (int i = 0; i < 4; ++i) o[i] = (f16)acc[i];
            if (gr < M) *(half4*)(Out + (size_t)gr * 128 + f * 16 + q * 4) = o;
        }
    }

    if (!mode2) {
        #pragma unroll
        for (int kk = 0; kk < 4; ++kk)
            a[kk] = *(const half8*)(xBuf + (R + n16) * 136 + kk * 32 + q * 8);
        #pragma unroll
        for (int f = 0; f < 8; ++f) {
            floatx4 acc = *(const floatx4*)(bias2 + f * 16 + q * 4);
            #pragma unroll
            for (int kk = 0; kk < 4; ++kk) {
                half8 aw = *(const half8*)(W2T + (f * 16 + n16) * 136 + kk * 32 + q * 8);
                acc = __builtin_amdgcn_mfma_f32_16x16x32_f16(aw, a[kk], acc, 0, 0, 0);
            }
            half4 o;
            #pragma unroll
            for (int i = 0; i < 4; ++i) o[i] = (f16)acc[i];
            if (gr < M) *(half4*)(Out + (size_t)gr * 128 + f * 16 + q * 4) = o;
        }
    }
}

// ---------------------------------------------------------------------------
// Barrier-free edge kernel, 32-edge chunks, 8 waves/block (512 thr) — THE
// VERIFIED SESSION OPTIMUM (675.8 us total / 139.0 us per dispatch, FETCH
// 80.6 MB, WRITE 26.0 MB, conflicts 1.99e7, VGPR 124, no spill).
// Each W2T/WcT/W1rT fragment read feeds TWO MFMAs (edges 0-15 / 16-31),
// cutting per-edge b128 LDS traffic ~45% vs the 16-wave R11 kernel (-27%
// bank conflicts, -6% time).
// TERMINAL STATE — every other direction measured and closed:
//  * Rtab distance tables (any size) add a random-request stream -> L2
//    displacement cascade, FETCH 80->189/245 MB (R1'/R2').
//  * Promoting biases or W1r to registers: compiler refuses to hold added
//    loop-invariant state across the fenced chunk loop (VGPR stays low,
//    scratch stream appears) -> same thrash, FETCH 230-249 MB (R3'/R6').
//  * 10 waves via LDS savings: blocked by the above (R6').
//  * 1-deep T prefetch into named regs: neutral within noise — T drain was
//    already L2-hot and covered (R7').
//  * Unfenced gathers: compiler pipelines P across iterations, FETCH 223 MB
//    (R8/R10). sched_barrier(0) fences are load-bearing.
// Remaining wall: serialized VALU<->LDS<->MFMA phase chain at 2 waves/SIMD
// (VALU 43%, LDS ~50%+23% conflict, MFMA 17%, HBM 9%); identified residual
// levers predict <5%, below the +/-5% cross-session noise floor.
// ---------------------------------------------------------------------------
__global__ __launch_bounds__(512, 2) void edge_kernel(
        const uint4* __restrict__ packE,
        const f16* __restrict__ P, const f16* __restrict__ T,
        const float* __restrict__ We1,
        const float* __restrict__ We2, const float* __restrict__ be2,
        const float* __restrict__ Wc,  const float* __restrict__ bc,
        float* __restrict__ h) {
    __shared__ f16 W2T[128 * 136];       // 34816 B
    __shared__ f16 WcT[128 * 136];       // 34816 B
    __shared__ f16 W1rT[128 * 40];       // 10240 B
    __shared__ f16 Uall[8 * 4352];       // 69632 B : per-wave 32x136 (T/u/ep) then mT
    __shared__ float sbe2[128], sbc[128];
    __shared__ int dstW[8][32];
    // total 151552 B -> 1 block/CU, 8 waves

    int tid = threadIdx.x;
    stage_WT(We2, W2T, tid, 512);
    stage_WT(Wc,  WcT, tid, 512);
    for (int idx = tid; idx < 128 * 32; idx += 512) {
        int n = idx >> 5, kr = idx & 31;
        W1rT[n * 40 + kr] = (kr < 30) ? (f16)We1[(128 + kr) * 128 + n] : (f16)0.0f;
    }
    if (tid < 128) { sbe2[tid] = be2[tid]; sbc[tid] = bc[tid]; }
    __syncthreads();    // weights ready; the ONLY block barrier

    int lane = tid & 63, wv = tid >> 6;      // wv 0..7
    f16* U = Uall + wv * 4352;
    int* dW = dstW[wv];
    int n16 = lane & 15, q = lane >> 4;
    const float invgap = 29.0f / 10.0f;
    int colA = lane, colB = lane + 64;
    int tsub = lane & 3, trow = lane >> 2;

    float sbcv[8];
    #pragma unroll
    for (int f = 0; f < 8; ++f) sbcv[f] = sbc[f * 16 + n16];

    // balanced stripe: 25000 chunks over 2048 waves (12 or 13 each)
    int wgid = blockIdx.x * 8 + wv;
    int extra = wgid < 424 ? wgid : 424;
    int c0 = wgid * 12 + extra;
    int c1 = c0 + 12 + (wgid < 424 ? 1 : 0);

    float carry0 = 0.0f, carry1 = 0.0f;
    int prev = -1;

    // prologue: pk for chunk c0 (32 records)
    uint4 pk = {0u, 0u, 0u, 0u};
    if (lane < 32) pk = packE[(size_t)c0 * 32 + lane];

    for (int ch = c0; ch < c1; ++ch) {
        bool hasNext = (ch + 1 < c1);
        // ---- distribute current records -----------------------------------
        int   ety0  = __shfl((int)pk.y, trow);
        int   ety1  = __shfl((int)pk.y, trow + 16);
        int   srcv0 = __shfl((int)pk.x, n16);
        int   srcv1 = __shfl((int)pk.x, n16 + 16);
        float d0    = __shfl(__uint_as_float(pk.w), n16);
        float d1    = __shfl(__uint_as_float(pk.w), n16 + 16);
        if (lane < 32) dW[lane] = (int)pk.z;

        // ---- T loads (both halves), drained into LDS (phase A) ------------
        {
            const uint4* Tp0 = (const uint4*)(T + (size_t)ety0 * 128 + tsub * 32);
            const uint4* Tp1 = (const uint4*)(T + (size_t)ety1 * 128 + tsub * 32);
            uint4 ta0 = Tp0[0], ta1 = Tp0[1], ta2 = Tp0[2], ta3 = Tp0[3];
            uint4 tb0 = Tp1[0], tb1 = Tp1[1], tb2 = Tp1[2], tb3 = Tp1[3];
            uint4* u0 = (uint4*)(U + trow * 136 + tsub * 32);
            uint4* u1 = (uint4*)(U + (16 + trow) * 136 + tsub * 32);
            u0[0] = ta0; u0[1] = ta1; u0[2] = ta2; u0[3] = ta3;
            u1[0] = tb0; u1[1] = tb1; u1[2] = tb2; u1[3] = tb3;
        }
        __builtin_amdgcn_sched_barrier(0);   // T drained before P issues

        // ---- NOW issue P loads (T no longer in flight) --------------------
        half8 pA0, pA1, pA2, pA3, pB0, pB1, pB2, pB3;
        {
            const f16* Pr0 = P + (size_t)srcv0 * 128 + q * 8;
            const f16* Pr1 = P + (size_t)srcv1 * 128 + q * 8;
            pA0 = *(const half8*)(Pr0);      pA1 = *(const half8*)(Pr0 + 32);
            pA2 = *(const half8*)(Pr0 + 64); pA3 = *(const half8*)(Pr0 + 96);
            pB0 = *(const half8*)(Pr1);      pB1 = *(const half8*)(Pr1 + 32);
            pB2 = *(const half8*)(Pr1 + 64); pB3 = *(const half8*)(Pr1 + 96);
        }
        uint4 pkn = {0u, 0u, 0u, 0u};
        if (hasNext && lane < 32) pkn = packE[(size_t)(ch + 1) * 32 + lane];

        // ---- rbf in regs (VALU overlaps P latency) ------------------------
        half8 ar0, ar1;
        #pragma unroll
        for (int j = 0; j < 8; ++j) {
            int k = q * 8 + j;
            float c = (float)k * (10.0f / 29.0f);
            float df0 = d0 - c, df1 = d1 - c;
            ar0[j] = (f16)((k < 30) ? __expf(-df0 * df0 * invgap) : 0.0f);
            ar1[j] = (f16)((k < 30) ? __expf(-df1 * df1 * invgap) : 0.0f);
        }

        // ---- B: u^T = relu(W1r^T @ rbf^T + T^T); 1 weight read, 2 MFMAs ---
        #pragma unroll
        for (int f = 0; f < 8; ++f) {
            half8 aw = *(const half8*)(W1rT + (f * 16 + n16) * 40 + q * 8);
            f16* up0 = U + n16 * 136 + f * 16 + q * 4;
            f16* up1 = U + (16 + n16) * 136 + f * 16 + q * 4;
            half4 tv0 = *(const half4*)up0;
            half4 tv1 = *(const half4*)up1;
            floatx4 c40 = {(float)tv0[0], (float)tv0[1], (float)tv0[2], (float)tv0[3]};
            floatx4 c41 = {(float)tv1[0], (float)tv1[1], (float)tv1[2], (float)tv1[3]};
            c40 = __builtin_amdgcn_mfma_f32_16x16x32_f16(aw, ar0, c40, 0, 0, 0);
            c41 = __builtin_amdgcn_mfma_f32_16x16x32_f16(aw, ar1, c41, 0, 0, 0);
            half4 uv0, uv1;
            #pragma unroll
            for (int i = 0; i < 4; ++i) {
                uv0[i] = (f16)fmaxf(c40[i], 0.0f);
                uv1[i] = (f16)fmaxf(c41[i], 0.0f);
            }
            *(half4*)up0 = uv0;
            *(half4*)up1 = uv1;
        }

        // ---- C: ep^T = W2^T @ u^T + be2; 1 weight read, 2 MFMAs -----------
        half8 a20[4], a21[4];
        #pragma unroll
        for (int kk = 0; kk < 4; ++kk) {
            a20[kk] = *(const half8*)(U + n16 * 136 + kk * 32 + q * 8);
            a21[kk] = *(const half8*)(U + (16 + n16) * 136 + kk * 32 + q * 8);
        }
        #pragma unroll
        for (int f = 0; f < 8; ++f) {
            floatx4 acc0 = *(const floatx4*)(sbe2 + f * 16 + q * 4);
            floatx4 acc1 = acc0;
            #pragma unroll
            for (int kk = 0; kk < 4; ++kk) {
                half8 aw = *(const half8*)(W2T + (f * 16 + n16) * 136 + kk * 32 + q * 8);
                acc0 = __builtin_amdgcn_mfma_f32_16x16x32_f16(aw, a20[kk], acc0, 0, 0, 0);
                acc1 = __builtin_amdgcn_mfma_f32_16x16x32_f16(aw, a21[kk], acc1, 0, 0, 0);
            }
            half4 ev0, ev1;
            #pragma unroll
            for (int i = 0; i < 4; ++i) { ev0[i] = (f16)acc0[i]; ev1[i] = (f16)acc1[i]; }
            *(half4*)(U + n16 * 136 + f * 16 + q * 4) = ev0;
            *(half4*)(U + (16 + n16) * 136 + f * 16 + q * 4) = ev1;
        }

        // ---- E: m = tanh((P ⊙ ep) @ Wc + bc); 1 weight read, 2 MFMAs ------
        {
            half8 e00 = *(const half8*)(U + n16 * 136 + 0 * 32 + q * 8);
            half8 e01 = *(const half8*)(U + n16 * 136 + 1 * 32 + q * 8);
            half8 e02 = *(const half8*)(U + n16 * 136 + 2 * 32 + q * 8);
            half8 e03 = *(const half8*)(U + n16 * 136 + 3 * 32 + q * 8);
            half8 e10 = *(const half8*)(U + (16 + n16) * 136 + 0 * 32 + q * 8);
            half8 e11 = *(const half8*)(U + (16 + n16) * 136 + 1 * 32 + q * 8);
            half8 e12 = *(const half8*)(U + (16 + n16) * 136 + 2 * 32 + q * 8);
            half8 e13 = *(const half8*)(U + (16 + n16) * 136 + 3 * 32 + q * 8);
            a20[0] = e00 * pA0; a20[1] = e01 * pA1; a20[2] = e02 * pA2; a20[3] = e03 * pA3;
            a21[0] = e10 * pB0; a21[1] = e11 * pB1; a21[2] = e12 * pB2; a21[3] = e13 * pB3;
        }
        #pragma unroll
        for (int f = 0; f < 8; ++f) {
            float bb = sbcv[f];
            floatx4 acc0 = {bb, bb, bb, bb};
            floatx4 acc1 = {bb, bb, bb, bb};
            #pragma unroll
            for (int kk = 0; kk < 4; ++kk) {
                half8 b = *(const half8*)(WcT + (f * 16 + n16) * 136 + kk * 32 + q * 8);
                acc0 = __builtin_amdgcn_mfma_f32_16x16x32_f16(a20[kk], b, acc0, 0, 0, 0);
                acc1 = __builtin_amdgcn_mfma_f32_16x16x32_f16(a21[kk], b, acc1, 0, 0, 0);
            }
            int c = f * 16 + n16;
            half4 mv0, mv1;
            #pragma unroll
            for (int i = 0; i < 4; ++i) {
                mv0[i] = (f16)fast_tanh(acc0[i]);
                mv1[i] = (f16)fast_tanh(acc1[i]);
            }
            *(half4*)(U + mt32(c, q))     = mv0;   // edges q*4..q*4+3
            *(half4*)(U + mt32(c, 4 + q)) = mv1;   // edges 16+q*4..16+q*4+3
        }

        // ---- F: per-col segment reduce over 32 rows with carry ------------
        {
            half4 va[8], vb[8];
            #pragma unroll
            for (int g = 0; g < 8; ++g) {
                va[g] = *(const half4*)(U + mt32(colA, g));
                vb[g] = *(const half4*)(U + mt32(colB, g));
            }
            int dArr[32];
            #pragma unroll
            for (int i4 = 0; i4 < 8; ++i4)
                *(int4*)(dArr + i4 * 4) = *(const int4*)(dW + i4 * 4);
            #pragma unroll
            for (int r = 0; r < 32; ++r) {
                int dd = dArr[r];
                float v0 = (float)va[r >> 2][r & 3];
                float v1 = (float)vb[r >> 2][r & 3];
                if (dd != prev) {   // wave-uniform branch
                    if (prev >= 0) {
                        unsafeAtomicAdd(&h[(size_t)prev * 128 + colA], carry0);
                        unsafeAtomicAdd(&h[(size_t)prev * 128 + colB], carry1);
                    }
                    prev = dd; carry0 = v0; carry1 = v1;
                } else { carry0 += v0; carry1 += v1; }
            }
        }
        pk = pkn;
        __builtin_amdgcn_sched_barrier(0);   // no cross-iteration load hoisting
    }
    if (prev >= 0) {
        unsafeAtomicAdd(&h[(size_t)prev * 128 + colA], carry0);
        unsafeAtomicAdd(&h[(size_t)prev * 128 + colB], carry1);
    }
}

// fused readout: hr = relu(h@Wr1+br1)·Wr2 + br2, out[gid] += hr  (per row)
__global__ __launch_bounds__(1024, 4) void readout_k(
        const float* __restrict__ X, int M,
        const float* __restrict__ W1, const float* __restrict__ b1,
        const float* __restrict__ Wr2, const float* __restrict__ br2,
        const int* __restrict__ gid, float* __restrict__ out) {
    __shared__ f16 W1T[128 * 136];
    __shared__ f16 xBuf[256 * 136];
    __shared__ float bias1[128];
    __shared__ float sWr2[128];
    int tid = threadIdx.x;

    stage_WT(W1, W1T, tid, 1024);
    if (tid < 128) { bias1[tid] = b1[tid]; sWr2[tid] = Wr2[tid]; }

    int r0 = blockIdx.x * 256;
    for (int it = 0; it < 8; ++it) {
        int row = it * 32 + (tid >> 5);
        int c4 = (tid & 31) * 4;
        int gr = r0 + row;
        floatx4 x = {0.0f, 0.0f, 0.0f, 0.0f};
        if (gr < M) x = *(const floatx4*)(X + (size_t)gr * 128 + c4);
        half4 xh;
        xh[0] = (f16)x[0]; xh[1] = (f16)x[1]; xh[2] = (f16)x[2]; xh[3] = (f16)x[3];
        *(half4*)(xBuf + row * 136 + c4) = xh;
    }
    __syncthreads();

    int lane = tid & 63, wv = tid >> 6;
    int R = wv * 16;
    int n16 = lane & 15, q = lane >> 4;

    half8 a[4];
    #pragma unroll
    for (int kk = 0; kk < 4; ++kk)
        a[kk] = *(const half8*)(xBuf + (R + n16) * 136 + kk * 32 + q * 8);

    floatx4 acc[8];
    #pragma unroll
    for (int f = 0; f < 8; ++f) {
        float bb = bias1[f * 16 + n16];
        acc[f] = (floatx4){bb, bb, bb, bb};
        #pragma unroll
        for (int kk = 0; kk < 4; ++kk) {
            half8 b = *(const half8*)(W1T + (f * 16 + n16) * 136 + kk * 32 + q * 8);
            acc[f] = __builtin_amdgcn_mfma_f32_16x16x32_f16(a[kk], b, acc[f], 0, 0, 0);
        }
    }

    float s[4];
    #pragma unroll
    for (int i = 0; i < 4; ++i) {
        float t = 0.0f;
        #pragma unroll
        for (int f = 0; f < 8; ++f)
            t += fmaxf(acc[f][i], 0.0f) * sWr2[f * 16 + n16];
        #pragma unroll
        for (int m = 1; m < 16; m <<= 1) t += __shfl_xor(t, m);
        s[i] = t;
    }

    if (n16 == 0) {
        float br2v = br2[0];
        float t = 0.0f; int g = -1;
        #pragma unroll
        for (int i = 0; i < 4; ++i) {
            int gr = r0 + R + q * 4 + i;
            if (gr < M) {
                int gi = gid[gr];
                float si = s[i] + br2v;
                if (gi == g) t += si;
                else { if (g >= 0) unsafeAtomicAdd(&out[g], t); g = gi; t = si; }
            }
        }
        if (g >= 0) unsafeAtomicAdd(&out[g], t);
    }
}

extern "C" void kernel_launch(void* const* d_in, const int* in_sizes, int n_in,
                              void* d_out, int out_size, void* d_ws, size_t ws_size,
                              hipStream_t stream) {
    (void)in_sizes; (void)n_in; (void)ws_size;
    const int*   node_types = (const int*)d_in[0];
    const int*   edge_types = (const int*)d_in[1];
    const int*   src        = (const int*)d_in[2];
    const int*   dst        = (const int*)d_in[3];
    const int*   graph_ids  = (const int*)d_in[4];
    const float* distances  = (const float*)d_in[5];
    const float* node_emb   = (const float*)d_in[7];
    const float* edge_emb   = (const float*)d_in[8];
    const float* Wn1 = (const float*)d_in[9];
    const float* bn1 = (const float*)d_in[10];
    const float* Wn2 = (const float*)d_in[11];
    const float* bn2 = (const float*)d_in[12];
    const float* We1 = (const float*)d_in[13];
    const float* be1 = (const float*)d_in[14];
    const float* We2 = (const float*)d_in[15];
    const float* be2 = (const float*)d_in[16];
    const float* Wc  = (const float*)d_in[17];
    const float* bc  = (const float*)d_in[18];
    const float* Wr1 = (const float*)d_in[19];
    const float* br1 = (const float*)d_in[20];
    const float* Wr2 = (const float*)d_in[21];
    const float* br2 = (const float*)d_in[22];

    char* w = (char*)d_ws;
    auto carve = [&](size_t bytes) { char* p = w; w += (bytes + 255) & ~(size_t)255; return p; };
    float* h        = (float*)carve((size_t)NNODES * 128 * 4);
    f16*   P        = (f16*)  carve((size_t)NNODES * 128 * 2);
    f16*   T        = (f16*)  carve((size_t)500 * 128 * 2);
    int*   rowStart = (int*)  carve((size_t)(NNODES + 1) * 4);
    int*   cnt      = (int*)  carve((size_t)NNODES * 4);
    int*   blockSum = (int*)  carve((size_t)64 * 4);
    uint4* packE    = (uint4*)carve((size_t)NEDGES * 16);

    float* out = (float*)d_out;
    const int NB1 = (NNODES + 1023) / 1024;   // 49

    init_k<<<(NNODES + 255) / 256, 256, 0, stream>>>(out, out_size, cnt);
    hist_k<<<NEDGES / 256, 256, 0, stream>>>(dst, cnt);
    scan1_k<<<NB1, 1024, 0, stream>>>(cnt, rowStart, blockSum);
    scan2_k<<<1, 64, 0, stream>>>(blockSum, NB1);
    scan3_k<<<NB1, 1024, 0, stream>>>(rowStart, blockSum, cnt);
    scatter_k<<<NEDGES / 256, 256, 0, stream>>>(src, edge_types, dst, distances,
                                                rowStart, cnt, packE);
    gather_h<<<(NNODES * 32 + 255) / 256, 256, 0, stream>>>(node_types, node_emb, h);

    for (int i = 0; i < 3; ++i) {
        mlp_combo<<<NB0 + 2, 1024, 0, stream>>>(
            h, Wn1 + (size_t)i * 128 * 128, bn1 + i * 128,
            Wn2 + (size_t)i * 128 * 128, bn2 + i * 128, P,
            edge_emb, We1 + (size_t)i * 158 * 128, be1 + i * 128, T);
        edge_kernel<<<256, 512, 0, stream>>>(
            packE, P, T,
            We1 + (size_t)i * 158 * 128,
            We2 + (size_t)i * 128 * 128, be2 + i * 128,
            Wc + (size_t)i * 128 * 128, bc + i * 128, h);
    }

    readout_k<<<(NNODES + 255) / 256, 1024, 0, stream>>>(
        h, NNODES, Wr1, br1, Wr2, br2, graph_ids, out);
}